// Round 1
// baseline (159.758 us; speedup 1.0000x reference)
//
#include <hip/hip_runtime.h>

#define NL 17
#define IGN (-100)
#define HD 384
#define NBAT 64
#define NSEQ 1024
#define NT (NBAT * NSEQ)   // 65536
#define BIGI NT

// ws layout: 32768 bytes total (assumes ws_size >= 32 KB)
struct WS {
  double ce_part[256];    // per-block CE partial sums
  double ctx_part[272];   // per-block ctx partial sums (+16 boundary blocks)
  int    ce_cnt[256];
  int    ctx_cnt[272];
  int    g_a[16];         // first index per entity type (1..16)
  int    g_cnt[16];       // count per entity type
  int    g_p[16];         // second index per entity type
  int    g_d;             // first non-entity index
  int    pad[31];
  float  wt[24 * NL * 16]; // W^T re-blocked: [chunk][class][16 elems]
};

// ---------------- prep: init scan mins + repack W ----------------
__global__ void k_prep(const float* __restrict__ cw, WS* __restrict__ ws) {
  int tid = threadIdx.x;
  if (tid < 16) { ws->g_a[tid] = BIGI; ws->g_p[tid] = BIGI; ws->g_cnt[tid] = 0; }
  if (tid == 16) ws->g_d = BIGI;
  for (int i = tid; i < 24 * NL * 16; i += 256) {
    int e  = i & 15;
    int c  = (i >> 4) % NL;
    int ch = i / (NL * 16);
    ws->wt[i] = cw[c * HD + ch * 16 + e];
  }
}

// ---------------- scan1: per-type first idx + counts, first non-entity ----------------
__global__ void k_scan1(const int* __restrict__ labels, const int* __restrict__ mask,
                        WS* __restrict__ ws) {
  __shared__ int la[16], lc[16], ld;
  int tid = threadIdx.x;
  if (tid < 16) { la[tid] = BIGI; lc[tid] = 0; }
  if (tid == 16) ld = BIGI;
  __syncthreads();
  for (int i = blockIdx.x * blockDim.x + tid; i < NT; i += gridDim.x * blockDim.x) {
    int lb = labels[i];
    if (mask[i] > 0) {
      if (lb == 0) atomicMin(&ld, i);
      else if (lb >= 1 && lb < NL) { atomicMin(&la[lb - 1], i); atomicAdd(&lc[lb - 1], 1); }
    }
  }
  __syncthreads();
  if (tid < 16) {
    atomicMin(&ws->g_a[tid], la[tid]);
    if (lc[tid]) atomicAdd(&ws->g_cnt[tid], lc[tid]);
  }
  if (tid == 16) atomicMin(&ws->g_d, ld);
}

// ---------------- scan2: per-type second idx (needs g_a final) ----------------
__global__ void k_scan2(const int* __restrict__ labels, const int* __restrict__ mask,
                        WS* __restrict__ ws) {
  __shared__ int lp[16], sa[16];
  int tid = threadIdx.x;
  if (tid < 16) { lp[tid] = BIGI; sa[tid] = ws->g_a[tid]; }
  __syncthreads();
  for (int i = blockIdx.x * blockDim.x + tid; i < NT; i += gridDim.x * blockDim.x) {
    int lb = labels[i];
    if (mask[i] > 0 && lb >= 1 && lb < NL && i > sa[lb - 1]) atomicMin(&lp[lb - 1], i);
  }
  __syncthreads();
  if (tid < 16) atomicMin(&ws->g_p[tid], lp[tid]);
}

// ---------------- main: fused CE (GEMV+log-softmax) + ctx MSE ----------------
__global__ __launch_bounds__(256) void k_main(const float* __restrict__ emb,
                                              const float* __restrict__ bias,
                                              const int* __restrict__ labels,
                                              WS* __restrict__ ws) {
  const int tid = threadIdx.x;
  const int lane = tid & 63;
  const int wid = tid >> 6;
  const int token = blockIdx.x * 256 + tid;
  const float4* __restrict__ row4 = (const float4*)(emb + (size_t)token * HD);
  const float* __restrict__ wt = ws->wt;

  float acc[NL];
#pragma unroll
  for (int c = 0; c < NL; ++c) acc[c] = bias[c];
  float ctxacc = 0.f;

  // depth-3 chunk pipeline; chunk = 16 floats (4 float4)
  float4 bufA[4], bufB[4], bufC[4];
#pragma unroll
  for (int q = 0; q < 4; ++q) { bufA[q] = row4[q]; bufB[q] = row4[4 + q]; bufC[q] = row4[8 + q]; }

  auto proc = [&](int ch, const float4* V) {
    float e_[16];
#pragma unroll
    for (int q = 0; q < 4; ++q) {
      e_[4 * q + 0] = V[q].x; e_[4 * q + 1] = V[q].y;
      e_[4 * q + 2] = V[q].z; e_[4 * q + 3] = V[q].w;
    }
    // ctx: neighbor token is neighbor lane
#pragma unroll
    for (int e = 0; e < 16; ++e) {
      float n = __shfl_down(e_[e], 1, 64);
      float d = e_[e] - n;
      ctxacc = fmaf(d, d, ctxacc);
    }
    // 17-class GEMV slice; w reads are wave-uniform contiguous -> scalar loads
    const float* wb = wt + ch * (NL * 16);
#pragma unroll
    for (int c = 0; c < NL; ++c) {
      const float* w16 = wb + c * 16;
      float a = acc[c];
#pragma unroll
      for (int e = 0; e < 16; ++e) a = fmaf(e_[e], w16[e], a);
      acc[c] = a;
    }
  };

#pragma unroll 1
  for (int ch = 0; ch < 24; ch += 3) {
    int pb = (ch + 3 <= 21) ? ch + 3 : 21;  // clamped prefetch (tail reloads from L1)
    float4 nA[4], nB[4], nC[4];
#pragma unroll
    for (int q = 0; q < 4; ++q) {
      nA[q] = row4[pb * 4 + q];
      nB[q] = row4[pb * 4 + 4 + q];
      nC[q] = row4[pb * 4 + 8 + q];
    }
    proc(ch, bufA); proc(ch + 1, bufB); proc(ch + 2, bufC);
#pragma unroll
    for (int q = 0; q < 4; ++q) { bufA[q] = nA[q]; bufB[q] = nB[q]; bufC[q] = nC[q]; }
  }

  // log-softmax + NLL (all in registers, no runtime indexing)
  float m = acc[0];
#pragma unroll
  for (int c = 1; c < NL; ++c) m = fmaxf(m, acc[c]);
  float s = 0.f;
#pragma unroll
  for (int c = 0; c < NL; ++c) s += __expf(acc[c] - m);
  float lse = m + __logf(s);
  int lb = labels[token];
  int safe = (lb == IGN) ? 0 : lb;
  float ll = 0.f;
#pragma unroll
  for (int c = 0; c < NL; ++c) ll = (c == safe) ? acc[c] : ll;
  bool valid = (lb != IGN);
  float cev = valid ? (lse - ll) : 0.f;

  int nlb = labels[(token + 1 < NT) ? token + 1 : NT - 1];
  bool rowend = ((token + 1) & (NSEQ - 1)) == 0;
  bool pair = (lane < 63) && !rowend && (lb != IGN) && (lb == nlb) && (lb > 0);
  float ctxv = pair ? ctxacc * (1.0f / HD) : 0.f;

  unsigned long long bv = __ballot(valid);
  unsigned long long bp = __ballot(pair);
#pragma unroll
  for (int off = 32; off; off >>= 1) {
    cev  += __shfl_xor(cev, off, 64);
    ctxv += __shfl_xor(ctxv, off, 64);
  }

  __shared__ float sce[4], sctx[4];
  __shared__ int svc[4], spc[4];
  if (lane == 0) { sce[wid] = cev; sctx[wid] = ctxv; svc[wid] = __popcll(bv); spc[wid] = __popcll(bp); }
  __syncthreads();
  if (tid == 0) {
    ws->ce_part[blockIdx.x]  = (double)sce[0] + sce[1] + sce[2] + sce[3];
    ws->ctx_part[blockIdx.x] = (double)sctx[0] + sctx[1] + sctx[2] + sctx[3];
    ws->ce_cnt[blockIdx.x]   = svc[0] + svc[1] + svc[2] + svc[3];
    ws->ctx_cnt[blockIdx.x]  = spc[0] + spc[1] + spc[2] + spc[3];
  }
}

// ---------------- boundary ctx pairs (token % 64 == 63) ----------------
__global__ void k_boundary(const float* __restrict__ emb, const int* __restrict__ labels,
                           WS* __restrict__ ws) {
  const int tid = threadIdx.x, lane = tid & 63, wid = tid >> 6;
  float sum = 0.f; int cnt = 0;
  for (int it = 0; it < 16; ++it) {
    int k = blockIdx.x * 64 + wid * 16 + it;
    int t = k * 64 + 63;
    if (((t + 1) & (NSEQ - 1)) == 0) continue;   // row boundary: not a pair
    int l0 = labels[t], l1 = labels[t + 1];
    if (l0 != IGN && l0 == l1 && l0 > 0) {
      const float* r0 = emb + (size_t)t * HD;
      const float* r1 = r0 + HD;
      float a = 0.f;
#pragma unroll
      for (int j = 0; j < 6; ++j) {
        float d = r0[lane + 64 * j] - r1[lane + 64 * j];
        a = fmaf(d, d, a);
      }
#pragma unroll
      for (int off = 32; off; off >>= 1) a += __shfl_xor(a, off, 64);
      sum += a * (1.0f / HD);
      cnt += 1;
    }
  }
  __shared__ float ss[4]; __shared__ int sc[4];
  if (lane == 0) { ss[wid] = sum; sc[wid] = cnt; }
  __syncthreads();
  if (tid == 0) {
    ws->ctx_part[256 + blockIdx.x] = (double)ss[0] + ss[1] + ss[2] + ss[3];
    ws->ctx_cnt[256 + blockIdx.x]  = sc[0] + sc[1] + sc[2] + sc[3];
  }
}

// ---------------- finalize: reduce partials + quadruplet loss + output ----------------
__global__ void k_final(const float* __restrict__ emb, WS* __restrict__ ws,
                        float* __restrict__ out) {
  const int tid = threadIdx.x, lane = tid & 63, wid = tid >> 6;
  __shared__ double rce[256], rctx[256];
  __shared__ int rvc[256], rpc[256];
  rce[tid]  = ws->ce_part[tid];
  rctx[tid] = ws->ctx_part[tid] + ((tid < 16) ? ws->ctx_part[256 + tid] : 0.0);
  rvc[tid]  = ws->ce_cnt[tid];
  rpc[tid]  = ws->ctx_cnt[tid] + ((tid < 16) ? ws->ctx_cnt[256 + tid] : 0);
  __syncthreads();
  for (int s = 128; s > 0; s >>= 1) {
    if (tid < s) {
      rce[tid] += rce[tid + s]; rctx[tid] += rctx[tid + s];
      rvc[tid] += rvc[tid + s]; rpc[tid] += rpc[tid + s];
    }
    __syncthreads();
  }

  // quadruplet: 4 waves x 4 types each
  __shared__ float qs[4]; __shared__ int qc[4];
  int ga[16];
#pragma unroll
  for (int u = 0; u < 16; ++u) ga[u] = ws->g_a[u];
  int gd = ws->g_d;
  float qsum = 0.f; int qcnt = 0;
  for (int tt = 0; tt < 4; ++tt) {
    int t = wid * 4 + tt;  // (type-1) in 0..15
    int a = ga[t], p = ws->g_p[t], c = ws->g_cnt[t];
    int nmin = BIGI;
#pragma unroll
    for (int u = 0; u < 16; ++u) if (u != t) nmin = min(nmin, ga[u]);
    bool ok = (c >= 2) && (nmin < BIGI) && (gd < BIGI);
    if (ok) {
      const float* A  = emb + (size_t)min(a, NT - 1) * HD;
      const float* P  = emb + (size_t)min(p, NT - 1) * HD;
      const float* Ng = emb + (size_t)min(nmin, NT - 1) * HD;
      const float* D  = emb + (size_t)min(gd, NT - 1) * HD;
      float sap = 0.f, san = 0.f, sad = 0.f;
#pragma unroll
      for (int j = 0; j < 6; ++j) {
        int idx = lane + 64 * j;
        float av = A[idx];
        float d1 = av - P[idx] + 1e-6f;  sap = fmaf(d1, d1, sap);
        float d2 = av - Ng[idx] + 1e-6f; san = fmaf(d2, d2, san);
        float d3 = av - D[idx] + 1e-6f;  sad = fmaf(d3, d3, sad);
      }
#pragma unroll
      for (int off = 32; off; off >>= 1) {
        sap += __shfl_xor(sap, off, 64);
        san += __shfl_xor(san, off, 64);
        sad += __shfl_xor(sad, off, 64);
      }
      float pd = sqrtf(sap), nd = sqrtf(san), dd = sqrtf(sad);
      float ql = fmaxf(pd - nd + 1.0f, 0.f) + fmaxf(pd - dd + 2.0f, 0.f);
      qsum += ql; qcnt += 1;
    }
  }
  if (lane == 0) { qs[wid] = qsum; qc[wid] = qcnt; }
  __syncthreads();
  if (tid == 0) {
    double tq = (double)qs[0] + qs[1] + qs[2] + qs[3];
    int tqc = qc[0] + qc[1] + qc[2] + qc[3];
    double ce   = rce[0] / (double)max(rvc[0], 1);
    double ctx  = (rpc[0] > 0) ? rctx[0] / (double)rpc[0] : 0.0;
    double quad = (tqc > 0) ? tq / (double)tqc : 0.0;
    out[0] = (float)(ce + 0.5 * quad + 0.1 * ctx);
  }
}

extern "C" void kernel_launch(void* const* d_in, const int* in_sizes, int n_in,
                              void* d_out, int out_size, void* d_ws, size_t ws_size,
                              hipStream_t stream) {
  const float* emb    = (const float*)d_in[0];
  const float* cw     = (const float*)d_in[1];
  const float* cb     = (const float*)d_in[2];
  const int*   labels = (const int*)d_in[3];
  const int*   mask   = (const int*)d_in[4];
  WS* ws = (WS*)d_ws;
  float* out = (float*)d_out;

  k_prep<<<1, 256, 0, stream>>>(cw, ws);
  k_scan1<<<64, 256, 0, stream>>>(labels, mask, ws);
  k_scan2<<<64, 256, 0, stream>>>(labels, mask, ws);
  k_main<<<NT / 256, 256, 0, stream>>>(emb, cb, labels, ws);
  k_boundary<<<16, 256, 0, stream>>>(emb, labels, ws);
  k_final<<<1, 256, 0, stream>>>(emb, ws, out);
}

// Round 2
// 135.676 us; speedup vs baseline: 1.1775x; 1.1775x over previous
//
#include <hip/hip_runtime.h>

#define NL 17
#define IGN (-100)
#define HD 384
#define NSEQ 1024
#define NT 65536
#define BIGI NT
#define NBLK_MAIN 1024
#define NBLK_SCAN 64

// ws usage: ~29.3 KB
struct WS {
  float ce_part[NBLK_MAIN];
  float ctx_part[NBLK_MAIN];
  int   ce_cnt[NBLK_MAIN];
  int   ctx_cnt[NBLK_MAIN];
  int   blk_a[NBLK_SCAN][16];  // per-block first idx per entity type
  int   blk_p[NBLK_SCAN][16];  // per-block second idx per entity type
  int   blk_c[NBLK_SCAN][16];  // per-block count per entity type
  int   blk_d[NBLK_SCAN];      // per-block first non-entity idx
};

// ---------------- scan: per-block label stats (no global atomics, no init kernel) ----
__global__ __launch_bounds__(256) void k_scan(const int* __restrict__ labels,
                                              const int* __restrict__ mask,
                                              WS* __restrict__ ws) {
  __shared__ int comp[1024];
  __shared__ int la[16], lc[16], lp[16], ld;
  const int tid = threadIdx.x, b = blockIdx.x;
  if (tid < 16) { la[tid] = BIGI; lc[tid] = 0; lp[tid] = BIGI; }
  if (tid == 16) ld = BIGI;
  __syncthreads();
  const int base = b * 1024;
#pragma unroll
  for (int k = 0; k < 4; ++k) {
    int l = tid + 256 * k, t = base + l;
    int lb = labels[t];
    int mk = mask[t];
    comp[l] = (mk > 0) ? lb : IGN;
    if (mk > 0) {
      if (lb == 0) atomicMin(&ld, t);
      else if (lb >= 1 && lb < NL) { atomicMin(&la[lb - 1], t); atomicAdd(&lc[lb - 1], 1); }
    }
  }
  __syncthreads();
#pragma unroll
  for (int k = 0; k < 4; ++k) {
    int l = tid + 256 * k, t = base + l;
    int c = comp[l];
    if (c >= 1 && c < NL && t > la[c - 1]) atomicMin(&lp[c - 1], t);
  }
  __syncthreads();
  if (tid < 16) {
    ws->blk_a[b][tid] = la[tid];
    ws->blk_p[b][tid] = lp[tid];
    ws->blk_c[b][tid] = lc[tid];
  }
  if (tid == 16) ws->blk_d[b] = ld;
}

// ---------------- main: 64 tokens/block, H split across 4 waves ----------------
__global__ __launch_bounds__(256) void k_main(const float* __restrict__ emb,
                                              const float* __restrict__ cw,
                                              const float* __restrict__ cb,
                                              const int* __restrict__ labels,
                                              WS* __restrict__ ws) {
  __shared__ float pl[4][64][NL];   // per-wave logit partials
  __shared__ float pc[4][64];       // per-wave ctx partials
  __shared__ float sbctx;
  __shared__ int   sbcnt;
  const int tid = threadIdx.x, lane = tid & 63, wid = tid >> 6;
  const int b = blockIdx.x;
  const int token = b * 64 + lane;
  const int colbase = wid * 96;
  const float4* __restrict__ rp = (const float4*)(emb + (size_t)token * HD + colbase);

  // load this lane's 96-float quarter-row in one burst (max MLP)
  float4 v[24];
#pragma unroll
  for (int q = 0; q < 24; ++q) v[q] = rp[q];

  float acc[NL];
#pragma unroll
  for (int c = 0; c < NL; ++c) acc[c] = 0.f;
  float ctxacc = 0.f;

#pragma unroll
  for (int ch = 0; ch < 6; ++ch) {
    float e_[16];
#pragma unroll
    for (int q = 0; q < 4; ++q) {
      e_[4 * q + 0] = v[4 * ch + q].x; e_[4 * q + 1] = v[4 * ch + q].y;
      e_[4 * q + 2] = v[4 * ch + q].z; e_[4 * q + 3] = v[4 * ch + q].w;
    }
    // ctx MSE partial: neighbor token = neighbor lane
#pragma unroll
    for (int e = 0; e < 16; ++e) {
      float n = __shfl_down(e_[e], 1, 64);
      float d = e_[e] - n;
      ctxacc = fmaf(d, d, ctxacc);
    }
    // 17-class GEMV partial; weight reads wave-uniform contiguous -> s_load
    const float* wb = cw + colbase + ch * 16;
#pragma unroll
    for (int c = 0; c < NL; ++c) {
      const float* w16 = wb + c * HD;
      float a = acc[c];
#pragma unroll
      for (int e = 0; e < 16; ++e) a = fmaf(e_[e], w16[e], a);
      acc[c] = a;
    }
  }
#pragma unroll
  for (int c = 0; c < NL; ++c) pl[wid][lane][c] = acc[c];
  pc[wid][lane] = ctxacc;
  __syncthreads();

  // ---- epilogue ----
  float ctxv = 0.f; int pcnt = 0;
  if (tid < 64) {  // wave 0: per-token softmax + CE + intra-wave ctx pairs
    float lg[NL];
#pragma unroll
    for (int c = 0; c < NL; ++c)
      lg[c] = cb[c] + pl[0][tid][c] + pl[1][tid][c] + pl[2][tid][c] + pl[3][tid][c];
    float m = lg[0];
#pragma unroll
    for (int c = 1; c < NL; ++c) m = fmaxf(m, lg[c]);
    float s = 0.f;
#pragma unroll
    for (int c = 0; c < NL; ++c) s += __expf(lg[c] - m);
    float lse = m + __logf(s);
    int lb = labels[token];
    int safe = (lb == IGN) ? 0 : lb;
    float ll = 0.f;
#pragma unroll
    for (int c = 0; c < NL; ++c) ll = (c == safe) ? lg[c] : ll;
    bool valid = (lb != IGN);
    float cev = valid ? (lse - ll) : 0.f;

    float cs = pc[0][tid] + pc[1][tid] + pc[2][tid] + pc[3][tid];
    int nlb = (token + 1 < NT) ? labels[token + 1] : IGN;
    bool pair = (tid < 63) && valid && (lb == nlb) && (lb > 0);
    float cv = pair ? cs * (1.0f / HD) : 0.f;

    unsigned long long bv = __ballot(valid);
    unsigned long long bp = __ballot(pair);
#pragma unroll
    for (int off = 32; off; off >>= 1) {
      cev += __shfl_xor(cev, off, 64);
      cv  += __shfl_xor(cv, off, 64);
    }
    if (tid == 0) {
      ws->ce_part[b] = cev;
      ws->ce_cnt[b]  = __popcll(bv);
      ctxv = cv; pcnt = __popcll(bp);
    }
  } else if (wid == 1) {  // wave 1: boundary pair (last token of this block)
    int t63 = b * 64 + 63;
    float bc = 0.f; int bn = 0;
    if (((t63 + 1) & (NSEQ - 1)) != 0) {   // not a sequence boundary (also guards t63+1<NT)
      int l0 = labels[t63], l1 = labels[t63 + 1];
      if (l0 != IGN && l0 == l1 && l0 > 0) {
        const float* r0 = emb + (size_t)t63 * HD;
        const float* r1 = r0 + HD;
        float a = 0.f;
#pragma unroll
        for (int j = 0; j < 6; ++j) {
          float d = r0[lane + 64 * j] - r1[lane + 64 * j];
          a = fmaf(d, d, a);
        }
#pragma unroll
        for (int off = 32; off; off >>= 1) a += __shfl_xor(a, off, 64);
        bc = a * (1.0f / HD); bn = 1;
      }
    }
    if (lane == 0) { sbctx = bc; sbcnt = bn; }
  }
  __syncthreads();
  if (tid == 0) {
    ws->ctx_part[b] = ctxv + sbctx;
    ws->ctx_cnt[b]  = pcnt + sbcnt;
  }
}

// ---------------- finalize ----------------
__global__ __launch_bounds__(256) void k_final(const float* __restrict__ emb,
                                               WS* __restrict__ ws,
                                               float* __restrict__ out) {
  __shared__ double rce[256], rctx[256];
  __shared__ int rvc[256], rpc[256];
  __shared__ int ga[16], gp[16], gc[16];
  __shared__ int gdsh;
  __shared__ float qs[4]; __shared__ int qc[4];
  const int tid = threadIdx.x, lane = tid & 63, wid = tid >> 6;

  // reduce per-block CE/ctx partials (1024 each)
  double sc = 0, sx = 0; int cv = 0, cp = 0;
#pragma unroll
  for (int k = 0; k < 4; ++k) {
    int i = tid * 4 + k;
    sc += ws->ce_part[i]; sx += ws->ctx_part[i];
    cv += ws->ce_cnt[i];  cp += ws->ctx_cnt[i];
  }
  rce[tid] = sc; rctx[tid] = sx; rvc[tid] = cv; rpc[tid] = cp;
  __syncthreads();
  for (int s = 128; s > 0; s >>= 1) {
    if (tid < s) {
      rce[tid] += rce[tid + s]; rctx[tid] += rctx[tid + s];
      rvc[tid] += rvc[tid + s]; rpc[tid] += rpc[tid + s];
    }
    __syncthreads();
  }

  // merge per-block label stats
  if (tid < 16) {
    int m1 = BIGI, m2 = BIGI, cnt = 0;
    for (int bb = 0; bb < NBLK_SCAN; ++bb) {
      int x = ws->blk_a[bb][tid];
      if (x < m1) { m2 = m1; m1 = x; } else if (x < m2) { m2 = x; }
      int y = ws->blk_p[bb][tid];
      if (y < m1) { m2 = m1; m1 = y; } else if (y < m2) { m2 = y; }
      cnt += ws->blk_c[bb][tid];
    }
    ga[tid] = m1; gp[tid] = m2; gc[tid] = cnt;
  }
  if (tid == 16) {
    int d = BIGI;
    for (int bb = 0; bb < NBLK_SCAN; ++bb) d = min(d, ws->blk_d[bb]);
    gdsh = d;
  }
  __syncthreads();

  // quadruplet loss: 4 waves x 4 types each
  const int gd = gdsh;
  float qsum = 0.f; int qcnt = 0;
  for (int tt = 0; tt < 4; ++tt) {
    int t = wid * 4 + tt;
    int a = ga[t], p = gp[t], c = gc[t];
    int nmin = BIGI;
#pragma unroll
    for (int u = 0; u < 16; ++u) if (u != t) nmin = min(nmin, ga[u]);
    bool ok = (c >= 2) && (nmin < BIGI) && (gd < BIGI);
    if (ok) {
      const float* A  = emb + (size_t)min(a, NT - 1) * HD;
      const float* P  = emb + (size_t)min(p, NT - 1) * HD;
      const float* Ng = emb + (size_t)min(nmin, NT - 1) * HD;
      const float* D  = emb + (size_t)min(gd, NT - 1) * HD;
      float sap = 0.f, san = 0.f, sad = 0.f;
#pragma unroll
      for (int j = 0; j < 6; ++j) {
        int idx = lane + 64 * j;
        float av = A[idx];
        float d1 = av - P[idx] + 1e-6f;  sap = fmaf(d1, d1, sap);
        float d2 = av - Ng[idx] + 1e-6f; san = fmaf(d2, d2, san);
        float d3 = av - D[idx] + 1e-6f;  sad = fmaf(d3, d3, sad);
      }
#pragma unroll
      for (int off = 32; off; off >>= 1) {
        sap += __shfl_xor(sap, off, 64);
        san += __shfl_xor(san, off, 64);
        sad += __shfl_xor(sad, off, 64);
      }
      float pd = sqrtf(sap), nd = sqrtf(san), dd = sqrtf(sad);
      qsum += fmaxf(pd - nd + 1.0f, 0.f) + fmaxf(pd - dd + 2.0f, 0.f);
      qcnt += 1;
    }
  }
  if (lane == 0) { qs[wid] = qsum; qc[wid] = qcnt; }
  __syncthreads();
  if (tid == 0) {
    double tq = (double)qs[0] + qs[1] + qs[2] + qs[3];
    int tqc = qc[0] + qc[1] + qc[2] + qc[3];
    double ce   = rce[0] / (double)max(rvc[0], 1);
    double ctx  = (rpc[0] > 0) ? rctx[0] / (double)rpc[0] : 0.0;
    double quad = (tqc > 0) ? tq / (double)tqc : 0.0;
    out[0] = (float)(ce + 0.5 * quad + 0.1 * ctx);
  }
}

extern "C" void kernel_launch(void* const* d_in, const int* in_sizes, int n_in,
                              void* d_out, int out_size, void* d_ws, size_t ws_size,
                              hipStream_t stream) {
  const float* emb    = (const float*)d_in[0];
  const float* cw     = (const float*)d_in[1];
  const float* cb     = (const float*)d_in[2];
  const int*   labels = (const int*)d_in[3];
  const int*   mask   = (const int*)d_in[4];
  WS* ws = (WS*)d_ws;
  float* out = (float*)d_out;

  k_scan <<<NBLK_SCAN, 256, 0, stream>>>(labels, mask, ws);
  k_main <<<NBLK_MAIN, 256, 0, stream>>>(emb, cw, cb, labels, ws);
  k_final<<<1, 256, 0, stream>>>(emb, ws, out);
}

// Round 3
// 110.501 us; speedup vs baseline: 1.4458x; 1.2278x over previous
//
#include <hip/hip_runtime.h>

#define NL 17
#define IGN (-100)
#define HD 384
#define NSEQ 1024
#define NT 65536
#define BIGI NT
#define TPB 256          // tokens per block == threads per block
#define NBLK_MAIN (NT / TPB)   // 256
#define NBLK_SCAN 64
#define NCHUNK 12        // 384 / 32
#define CCOLS 32
#define CF4 8            // float4 per row per chunk

struct WS {
  float ce_part[NBLK_MAIN];
  float ctx_part[NBLK_MAIN];
  int   ce_cnt[NBLK_MAIN];
  int   ctx_cnt[NBLK_MAIN];
  int   blk_a[NBLK_SCAN][16];
  int   blk_p[NBLK_SCAN][16];
  int   blk_c[NBLK_SCAN][16];
  int   blk_d[NBLK_SCAN];
};

// ---------------- scan: per-block label stats ----------------
__global__ __launch_bounds__(256) void k_scan(const int* __restrict__ labels,
                                              const int* __restrict__ mask,
                                              WS* __restrict__ ws) {
  __shared__ int comp[1024];
  __shared__ int la[16], lc[16], lp[16], ld;
  const int tid = threadIdx.x, b = blockIdx.x;
  if (tid < 16) { la[tid] = BIGI; lc[tid] = 0; lp[tid] = BIGI; }
  if (tid == 16) ld = BIGI;
  __syncthreads();
  const int base = b * 1024;
#pragma unroll
  for (int k = 0; k < 4; ++k) {
    int l = tid + 256 * k, t = base + l;
    int lb = labels[t];
    int mk = mask[t];
    comp[l] = (mk > 0) ? lb : IGN;
    if (mk > 0) {
      if (lb == 0) atomicMin(&ld, t);
      else if (lb >= 1 && lb < NL) { atomicMin(&la[lb - 1], t); atomicAdd(&lc[lb - 1], 1); }
    }
  }
  __syncthreads();
#pragma unroll
  for (int k = 0; k < 4; ++k) {
    int l = tid + 256 * k, t = base + l;
    int c = comp[l];
    if (c >= 1 && c < NL && t > la[c - 1]) atomicMin(&lp[c - 1], t);
  }
  __syncthreads();
  if (tid < 16) {
    ws->blk_a[b][tid] = la[tid];
    ws->blk_p[b][tid] = lp[tid];
    ws->blk_c[b][tid] = lc[tid];
  }
  if (tid == 16) ws->blk_d[b] = ld;
}

// ---------------- main: 256 tokens/block, LDS-staged coalesced streaming ----------------
__global__ __launch_bounds__(256) void k_main(const float* __restrict__ emb,
                                              const float* __restrict__ cw,
                                              const float* __restrict__ cb,
                                              const int* __restrict__ labels,
                                              WS* __restrict__ ws) {
  __shared__ float4 tile[TPB][CF4];   // 32 KB, slot = c4 ^ (row&7)
  __shared__ float sce[4], sctx[4];
  __shared__ int   svc[4], spc[4];
  __shared__ float sbctx;
  __shared__ int   sbcnt;

  const int tid = threadIdx.x, lane = tid & 63, wid = tid >> 6;
  const int b = blockIdx.x;
  const int token = b * TPB + tid;
  const float4* __restrict__ emb4 = (const float4*)emb;
  const size_t base4 = (size_t)b * TPB * (HD / 4);

  // staging coordinates for this thread's 8 float4 (fixed across chunks)
  // l = tid + k*256 -> row = l>>3, c4 = l&7 : 8-lane group = one 128B line
  int srow[CF4], sc4[CF4];
#pragma unroll
  for (int k = 0; k < CF4; ++k) { int l = tid + k * TPB; srow[k] = l >> 3; sc4[k] = l & 7; }

  float acc[NL];
#pragma unroll
  for (int c = 0; c < NL; ++c) acc[c] = 0.f;
  float ctxacc = 0.f;

  float4 pf[CF4];
#pragma unroll
  for (int k = 0; k < CF4; ++k)
    pf[k] = emb4[base4 + (size_t)srow[k] * (HD / 4) + sc4[k]];   // chunk 0

  const int r0 = tid;
  const int r1 = (tid < TPB - 1) ? tid + 1 : tid;   // neighbor row (clamped)

#pragma unroll 1
  for (int ch = 0; ch < NCHUNK; ++ch) {
    __syncthreads();   // previous chunk's LDS reads complete
#pragma unroll
    for (int k = 0; k < CF4; ++k)
      tile[srow[k]][sc4[k] ^ (srow[k] & 7)] = pf[k];
    __syncthreads();

    if (ch + 1 < NCHUNK) {
#pragma unroll
      for (int k = 0; k < CF4; ++k)
        pf[k] = emb4[base4 + (size_t)srow[k] * (HD / 4) + (ch + 1) * CF4 + sc4[k]];
    }

    // compute this chunk from LDS: own row -> e0[32]; ctx vs neighbor row on the fly
    float e0[CCOLS];
#pragma unroll
    for (int q = 0; q < CF4; ++q) {
      float4 a = tile[r0][q ^ (r0 & 7)];
      float4 nb = tile[r1][q ^ (r1 & 7)];
      e0[4 * q + 0] = a.x; e0[4 * q + 1] = a.y; e0[4 * q + 2] = a.z; e0[4 * q + 3] = a.w;
      float d0 = a.x - nb.x, d1 = a.y - nb.y, d2 = a.z - nb.z, d3 = a.w - nb.w;
      ctxacc = fmaf(d0, d0, ctxacc); ctxacc = fmaf(d1, d1, ctxacc);
      ctxacc = fmaf(d2, d2, ctxacc); ctxacc = fmaf(d3, d3, ctxacc);
    }
    const float* wb = cw + ch * CCOLS;   // wave-uniform -> scalar loads
#pragma unroll
    for (int c = 0; c < NL; ++c) {
      const float* wrow = wb + c * HD;
      float a = acc[c];
#pragma unroll
      for (int e = 0; e < CCOLS; ++e) a = fmaf(e0[e], wrow[e], a);
      acc[c] = a;
    }
  }

  // ---- epilogue: softmax + CE + ctx pair, block reduce ----
  float m = acc[0] + cb[0];
#pragma unroll
  for (int c = 0; c < NL; ++c) acc[c] += cb[c];
#pragma unroll
  for (int c = 1; c < NL; ++c) m = fmaxf(m, acc[c]);
  float s = 0.f;
#pragma unroll
  for (int c = 0; c < NL; ++c) s += __expf(acc[c] - m);
  float lse = m + __logf(s);
  int lb = labels[token];
  int safe = (lb == IGN) ? 0 : lb;
  float ll = 0.f;
#pragma unroll
  for (int c = 0; c < NL; ++c) ll = (c == safe) ? acc[c] : ll;
  bool valid = (lb != IGN);
  float cev = valid ? (lse - ll) : 0.f;

  int nlb = (tid < TPB - 1) ? labels[token + 1] : IGN;  // cross-block pair handled below
  bool pair = (tid < TPB - 1) && valid && (lb == nlb) && (lb > 0);
  float ctxv = pair ? ctxacc * (1.0f / HD) : 0.f;

  unsigned long long bv = __ballot(valid);
  unsigned long long bp = __ballot(pair);
#pragma unroll
  for (int off = 32; off; off >>= 1) {
    cev  += __shfl_xor(cev, off, 64);
    ctxv += __shfl_xor(ctxv, off, 64);
  }
  if (lane == 0) { sce[wid] = cev; sctx[wid] = ctxv; svc[wid] = __popcll(bv); spc[wid] = __popcll(bp); }

  if (wid == 3) {   // boundary pair: (b*256+255, b*256+256)
    int t = b * TPB + TPB - 1;
    float bc = 0.f; int bn = 0;
    if (((t + 1) & (NSEQ - 1)) != 0) {   // not a sequence end (also guards t+1 < NT)
      int l0 = labels[t], l1 = labels[t + 1];
      if (l0 != IGN && l0 == l1 && l0 > 0) {
        const float* ra = emb + (size_t)t * HD;
        const float* rb = ra + HD;
        float a = 0.f;
#pragma unroll
        for (int j = 0; j < 6; ++j) {
          float d = ra[lane + 64 * j] - rb[lane + 64 * j];
          a = fmaf(d, d, a);
        }
#pragma unroll
        for (int off = 32; off; off >>= 1) a += __shfl_xor(a, off, 64);
        bc = a * (1.0f / HD); bn = 1;
      }
    }
    if (lane == 0) { sbctx = bc; sbcnt = bn; }
  }
  __syncthreads();
  if (tid == 0) {
    ws->ce_part[b]  = sce[0] + sce[1] + sce[2] + sce[3];
    ws->ce_cnt[b]   = svc[0] + svc[1] + svc[2] + svc[3];
    ws->ctx_part[b] = sctx[0] + sctx[1] + sctx[2] + sctx[3] + sbctx;
    ws->ctx_cnt[b]  = spc[0] + spc[1] + spc[2] + spc[3] + sbcnt;
  }
}

// ---------------- finalize ----------------
__global__ __launch_bounds__(256) void k_final(const float* __restrict__ emb,
                                               WS* __restrict__ ws,
                                               float* __restrict__ out) {
  __shared__ double rce[256], rctx[256];
  __shared__ int rvc[256], rpc[256];
  __shared__ int ga[16], gp[16], gc[16];
  __shared__ int gdsh;
  __shared__ float qs[4]; __shared__ int qc[4];
  const int tid = threadIdx.x, lane = tid & 63, wid = tid >> 6;

  rce[tid]  = ws->ce_part[tid];
  rctx[tid] = ws->ctx_part[tid];
  rvc[tid]  = ws->ce_cnt[tid];
  rpc[tid]  = ws->ctx_cnt[tid];
  __syncthreads();
  for (int s = 128; s > 0; s >>= 1) {
    if (tid < s) {
      rce[tid] += rce[tid + s]; rctx[tid] += rctx[tid + s];
      rvc[tid] += rvc[tid + s]; rpc[tid] += rpc[tid + s];
    }
    __syncthreads();
  }

  if (tid < 16) {
    int m1 = BIGI, m2 = BIGI, cnt = 0;
    for (int bb = 0; bb < NBLK_SCAN; ++bb) {
      int x = ws->blk_a[bb][tid];
      if (x < m1) { m2 = m1; m1 = x; } else if (x < m2) { m2 = x; }
      int y = ws->blk_p[bb][tid];
      if (y < m1) { m2 = m1; m1 = y; } else if (y < m2) { m2 = y; }
      cnt += ws->blk_c[bb][tid];
    }
    ga[tid] = m1; gp[tid] = m2; gc[tid] = cnt;
  }
  if (tid == 16) {
    int d = BIGI;
    for (int bb = 0; bb < NBLK_SCAN; ++bb) d = min(d, ws->blk_d[bb]);
    gdsh = d;
  }
  __syncthreads();

  const int gd = gdsh;
  float qsum = 0.f; int qcnt = 0;
  for (int tt = 0; tt < 4; ++tt) {
    int t = wid * 4 + tt;
    int a = ga[t], p = gp[t], c = gc[t];
    int nmin = BIGI;
#pragma unroll
    for (int u = 0; u < 16; ++u) if (u != t) nmin = min(nmin, ga[u]);
    bool ok = (c >= 2) && (nmin < BIGI) && (gd < BIGI);
    if (ok) {
      const float* A  = emb + (size_t)min(a, NT - 1) * HD;
      const float* P  = emb + (size_t)min(p, NT - 1) * HD;
      const float* Ng = emb + (size_t)min(nmin, NT - 1) * HD;
      const float* D  = emb + (size_t)min(gd, NT - 1) * HD;
      float sap = 0.f, san = 0.f, sad = 0.f;
#pragma unroll
      for (int j = 0; j < 6; ++j) {
        int idx = lane + 64 * j;
        float av = A[idx];
        float d1 = av - P[idx] + 1e-6f;  sap = fmaf(d1, d1, sap);
        float d2 = av - Ng[idx] + 1e-6f; san = fmaf(d2, d2, san);
        float d3 = av - D[idx] + 1e-6f;  sad = fmaf(d3, d3, sad);
      }
#pragma unroll
      for (int off = 32; off; off >>= 1) {
        sap += __shfl_xor(sap, off, 64);
        san += __shfl_xor(san, off, 64);
        sad += __shfl_xor(sad, off, 64);
      }
      float pd = sqrtf(sap), nd = sqrtf(san), dd = sqrtf(sad);
      qsum += fmaxf(pd - nd + 1.0f, 0.f) + fmaxf(pd - dd + 2.0f, 0.f);
      qcnt += 1;
    }
  }
  if (lane == 0) { qs[wid] = qsum; qc[wid] = qcnt; }
  __syncthreads();
  if (tid == 0) {
    double tq = (double)qs[0] + qs[1] + qs[2] + qs[3];
    int tqc = qc[0] + qc[1] + qc[2] + qc[3];
    double ce   = rce[0] / (double)max(rvc[0], 1);
    double ctx  = (rpc[0] > 0) ? rctx[0] / (double)rpc[0] : 0.0;
    double quad = (tqc > 0) ? tq / (double)tqc : 0.0;
    out[0] = (float)(ce + 0.5 * quad + 0.1 * ctx);
  }
}

extern "C" void kernel_launch(void* const* d_in, const int* in_sizes, int n_in,
                              void* d_out, int out_size, void* d_ws, size_t ws_size,
                              hipStream_t stream) {
  const float* emb    = (const float*)d_in[0];
  const float* cw     = (const float*)d_in[1];
  const float* cb     = (const float*)d_in[2];
  const int*   labels = (const int*)d_in[3];
  const int*   mask   = (const int*)d_in[4];
  WS* ws = (WS*)d_ws;
  float* out = (float*)d_out;

  k_scan <<<NBLK_SCAN, 256, 0, stream>>>(labels, mask, ws);
  k_main <<<NBLK_MAIN, 256, 0, stream>>>(emb, cw, cb, labels, ws);
  k_final<<<1, 256, 0, stream>>>(emb, ws, out);
}